// Round 13
// baseline (380.307 us; speedup 1.0000x reference)
//
#include <hip/hip_runtime.h>
#include <hip/hip_bf16.h>

// Decoder: one-hot@Wx gather -> 64-step LSTM -> Bahdanau attention softmax.
// B=32, T=64, S=64, U=512, 4U=2048, VOCAB=65.
//
// Round 12: lazy batched d1 polling. r11's pipelined-d1 fusion regressed the
// recurrence 314.7 -> 371.7us: 128 d1 waves tight-polling (s_sleep(2), ~50ns)
// the two 128B flag lines with device-scope loads queued against the
// producers' flag stores + LSTM detect polls. Fix (pre-committed): d1 wait =
// one coalesced flag load -> butterfly-MIN = ready -> process ALL owned
// timesteps <= ready in a batch -> only if none ready, s_sleep(64) (~1.7us).
// ~30-60x less flag traffic; recurrence path untouched (r10's 4.93us/step
// shape). Everything else identical to r11 (65 monotonic slots, h_64
// published, dec_u/proj deleted).

#define NB 32
#define NT 64
#define NS 64
#define NU 512
#define N4U 2048
#define NV 65
#define NWG 32

typedef unsigned int u32;
typedef __bf16 bf16_t;
typedef bf16_t bf16x8 __attribute__((ext_vector_type(8)));
typedef float f32x4 __attribute__((ext_vector_type(4)));
typedef u32 u32x4 __attribute__((ext_vector_type(4)));

__device__ __forceinline__ unsigned short f2bf(float f) {
  u32 u = __builtin_bit_cast(u32, f);
  u += 0x7fffu + ((u >> 16) & 1u);   // round-to-nearest-even
  return (unsigned short)(u >> 16);
}
__device__ __forceinline__ float bf2f(unsigned short s) {
  return __builtin_bit_cast(float, (u32)s << 16);
}
__device__ __forceinline__ u32 pk2(float a, float b) {
  return (u32)f2bf(a) | ((u32)f2bf(b) << 16);
}
__device__ __forceinline__ float sigf(float x) { return 1.0f / (1.0f + __expf(-x)); }
__device__ __forceinline__ float tanhfast(float x) {
  float e = __expf(2.0f * x);
  return 1.0f - 2.0f / (e + 1.0f);
}

// 16 slot-loads (sc0 sc1, L1-bypassing) -> A-fragments, waited IN-BLOCK.
#define LOAD_HSLOT(DST, AP)                                                   \
  asm volatile(                                                               \
    "global_load_dwordx4 %0, %16, off sc0 sc1\n\t"                            \
    "global_load_dwordx4 %1, %16, off offset:64 sc0 sc1\n\t"                  \
    "global_load_dwordx4 %2, %16, off offset:128 sc0 sc1\n\t"                 \
    "global_load_dwordx4 %3, %16, off offset:192 sc0 sc1\n\t"                 \
    "global_load_dwordx4 %4, %16, off offset:256 sc0 sc1\n\t"                 \
    "global_load_dwordx4 %5, %16, off offset:320 sc0 sc1\n\t"                 \
    "global_load_dwordx4 %6, %16, off offset:384 sc0 sc1\n\t"                 \
    "global_load_dwordx4 %7, %16, off offset:448 sc0 sc1\n\t"                 \
    "global_load_dwordx4 %8, %16, off offset:512 sc0 sc1\n\t"                 \
    "global_load_dwordx4 %9, %16, off offset:576 sc0 sc1\n\t"                 \
    "global_load_dwordx4 %10, %16, off offset:640 sc0 sc1\n\t"                \
    "global_load_dwordx4 %11, %16, off offset:704 sc0 sc1\n\t"                \
    "global_load_dwordx4 %12, %16, off offset:768 sc0 sc1\n\t"                \
    "global_load_dwordx4 %13, %16, off offset:832 sc0 sc1\n\t"                \
    "global_load_dwordx4 %14, %16, off offset:896 sc0 sc1\n\t"                \
    "global_load_dwordx4 %15, %16, off offset:960 sc0 sc1\n\t"                \
    "s_waitcnt vmcnt(0)"                                                      \
    : "=&v"(DST[0]),  "=&v"(DST[1]),  "=&v"(DST[2]),  "=&v"(DST[3]),          \
      "=&v"(DST[4]),  "=&v"(DST[5]),  "=&v"(DST[6]),  "=&v"(DST[7]),          \
      "=&v"(DST[8]),  "=&v"(DST[9]),  "=&v"(DST[10]), "=&v"(DST[11]),         \
      "=&v"(DST[12]), "=&v"(DST[13]), "=&v"(DST[14]), "=&v"(DST[15])          \
    : "v"(AP)                                                                 \
    : "memory")

// ---------------------------------------------------------------------------
// Mega kernel, grid 64 x 256.
//   wgs 0..31:  LSTM recurrence (wg g owns h units [g*16,g*16+16)).
//   wgs 32..63: e2 = enc@W2+b2 (64 rows each), then LAZY pipelined
//               d1 = h_t@W1+b1 for cols [16k,16k+16), t = 1..64.
// hbuf: [65 slots][32][256] u32 bf16-pairs (slot t = h_t; monotonic).
// flags: [32] per-wg epoch, memset 0 per launch; flag set only post-ack.
// ---------------------------------------------------------------------------
__global__ __launch_bounds__(256, 1)
void lstm_kernel(const int* __restrict__ labels,
                 const float* __restrict__ h0,
                 const float* __restrict__ c0,
                 const float* __restrict__ Wx,
                 const float* __restrict__ Wh,
                 const float* __restrict__ bias,
                 const float* __restrict__ enc,
                 const float* __restrict__ W2,
                 const float* __restrict__ b2,
                 const float* __restrict__ W1,
                 const float* __restrict__ b1,
                 u32* __restrict__ hbuf,    // [65][32][256] bf16-pairs
                 u32* __restrict__ flags,   // [32] per-wg epoch (memset 0)
                 unsigned short* __restrict__ d1_bf,
                 unsigned short* __restrict__ e2_bf)
{
  __shared__ float z_buf[NB][65];            // padded: conflict-free gate reads
  __shared__ float c_lds[NB][16];
  __shared__ float wx_lds[NV][65];           // Wx slice + bias folded, padded
  __shared__ unsigned char lab_lds[NB * NT]; // labels cached (values < 65)

  const int tid  = threadIdx.x;
  const int g    = blockIdx.x;
  const int wave = tid >> 6, lane = tid & 63;
  const int l15  = lane & 15, l4 = lane >> 4;

  // ------------------- e2 + lazy pipelined d1 wgs (32..63) -----------------
  if (g >= NWG) {
    const int k = g - NWG;                       // 0..31
    // ---- e2: rows [k*64, k*64+64), 16 per wave ----
    {
      const int r0 = k * 64 + wave * 16;
      const int arowE = r0 + l15;
      u32x4 afragE[16];
#pragma unroll
      for (int kt = 0; kt < 16; ++kt) {
        const float* ep = enc + arowE * NU + kt * 32 + l4 * 8;
        u32x4 t;
        t.x = pk2(ep[0], ep[1]); t.y = pk2(ep[2], ep[3]);
        t.z = pk2(ep[4], ep[5]); t.w = pk2(ep[6], ep[7]);
        afragE[kt] = t;
      }
      for (int cg = 0; cg < 8; ++cg) {
        f32x4 acc[4] = {};
        for (int kt = 0; kt < 16; ++kt) {
          bf16x8 a = __builtin_bit_cast(bf16x8, afragE[kt]);
          int k0 = kt * 32 + l4 * 8;
#pragma unroll
          for (int nt = 0; nt < 4; ++nt) {
            int col = cg * 64 + nt * 16 + l15;
            union { unsigned short us[8]; bf16x8 v; } bu;
#pragma unroll
            for (int e = 0; e < 8; ++e) bu.us[e] = f2bf(W2[(k0 + e) * NU + col]);
            acc[nt] = __builtin_amdgcn_mfma_f32_16x16x32_bf16(a, bu.v, acc[nt], 0, 0, 0);
          }
        }
#pragma unroll
        for (int nt = 0; nt < 4; ++nt) {
          int col = cg * 64 + nt * 16 + l15;
          float bc = b2[col];
#pragma unroll
          for (int ri = 0; ri < 4; ++ri)
            e2_bf[(r0 + l4 * 4 + ri) * NU + col] = f2bf(acc[nt][ri] + bc);
        }
      }
    }

    // ---- d1: cols [16k, 16k+16); wave (wm,wn): wm = batch half, wn =
    //      timestep parity. LAZY: batched min-ready poll; s_sleep(64)
    //      (~1.7us) only when nothing is ready. Slots monotonic => any lag
    //      safe; flag traffic ~30-60x lower than r11's tight poll. ----
    {
      const int wm = wave >> 1, wn = wave & 1;
      const int col = k * 16 + l15;
      const float bc1 = b1[col];
      bf16x8 bfrag1[16];
#pragma unroll
      for (int kt = 0; kt < 16; ++kt) {
        int kb = kt * 32 + l4 * 8;
        union { unsigned short us[8]; bf16x8 v; } bu;
#pragma unroll
        for (int e = 0; e < 8; ++e) bu.us[e] = f2bf(W1[(kb + e) * NU + col]);
        bfrag1[kt] = bu.v;
      }
      const int arow1 = wm * 16 + l15;             // batch row of A-frag
      int t = 1 + wn;
      int guard = 0;
      while (t <= NT) {
        // one coalesced flag load; butterfly-min => ready (all lanes)
        u32 f = 0xffffffffu;
        if (lane < NWG)
          f = __hip_atomic_load(flags + lane, __ATOMIC_RELAXED,
                                __HIP_MEMORY_SCOPE_AGENT);
#pragma unroll
        for (int o = 32; o > 0; o >>= 1) {
          u32 other = __shfl_xor(f, o);
          f = f < other ? f : other;
        }
        if (f >= (u32)t) {
          int ready = (f > (u32)NT) ? NT : (int)f;
          for (; t <= ready; t += 2) {             // batch all owned ready t
            u32x4 hf[16];
            const u32* ap1 = hbuf + (size_t)t * 8192 + arow1 * 256 + l4 * 4;
            LOAD_HSLOT(hf, ap1);
            f32x4 acc = {0.f, 0.f, 0.f, 0.f};
#pragma unroll
            for (int kt = 0; kt < 16; ++kt)
              acc = __builtin_amdgcn_mfma_f32_16x16x32_bf16(
                      __builtin_bit_cast(bf16x8, hf[kt]), bfrag1[kt], acc, 0, 0, 0);
#pragma unroll
            for (int ri = 0; ri < 4; ++ri) {
              int b = wm * 16 + l4 * 4 + ri;
              d1_bf[(b * NT + (t - 1)) * NU + col] = f2bf(acc[ri] + bc1);
            }
          }
        } else {
          if (++guard > 20000) break;      // anti-hang (~34ms) => absmax fail
          __builtin_amdgcn_s_sleep(64);    // ~4096 cyc ~= 1.7us lazy wait
        }
      }
    }
    return;
  }

  // ------------------------- LSTM wgs (0..31) ------------------------------
  const int wm = wave >> 1, wn = wave & 1;

  for (int i = tid; i < NV * 64; i += 256) {
    int v = i >> 6, c = i & 63;
    int j = (c >> 4) * NU + g * 16 + (c & 15);
    wx_lds[v][c] = Wx[v * N4U + j] + bias[j];
  }
  for (int i = tid; i < NB * 16; i += 256) {
    int r = i >> 4, u = i & 15;
    c_lds[r][u] = c0[r * NU + g * 16 + u];
  }
  for (int i = tid; i < NB * NT; i += 256) lab_lds[i] = (unsigned char)labels[i];

  // Wh B-fragments -> VGPRs, once (layout validated r1-r11).
  bf16x8 bfrag[16][2];
#pragma unroll
  for (int kt = 0; kt < 16; ++kt) {
#pragma unroll
    for (int nt = 0; nt < 2; ++nt) {
      int c = wn * 32 + nt * 16 + l15;
      int j = (c >> 4) * NU + g * 16 + (c & 15);
      int kb = kt * 32 + l4 * 8;
      union { unsigned short us[8]; bf16x8 v; } bu;
#pragma unroll
      for (int e = 0; e < 8; ++e) bu.us[e] = f2bf(Wh[(kb + e) * N4U + j]);
      bfrag[kt][nt] = bu.v;
    }
  }

  // A-fragments from h0: lane holds h[arow][kt*32 + l4*8 + e], e=0..7.
  const int arow = wm * 16 + l15;
  u32x4 afrag[16];
#pragma unroll
  for (int kt = 0; kt < 16; ++kt) {
    const float* hp = h0 + arow * NU + kt * 32 + l4 * 8;
    u32x4 t;
    t.x = pk2(hp[0], hp[1]); t.y = pk2(hp[2], hp[3]);
    t.z = pk2(hp[4], hp[5]); t.w = pk2(hp[6], hp[7]);
    afrag[kt] = t;
  }

  const int bb = tid >> 3;          // batch handled in update phase
  const int u2 = (tid & 7) * 2;     // unit pair
  const int ci = g * 8 + (tid & 7); // u32 col in [32][256] h layout

  for (int s = 0; s < NT; ++s) {
    // [B] z = h @ WhSlice  (4 chains; afrag valid: loads waited in-block)
    f32x4 a00 = {0.f,0.f,0.f,0.f}, a01 = a00, a10 = a00, a11 = a00;
#pragma unroll
    for (int kt = 0; kt < 16; kt += 2) {
      bf16x8 av0 = __builtin_bit_cast(bf16x8, afrag[kt]);
      bf16x8 av1 = __builtin_bit_cast(bf16x8, afrag[kt + 1]);
      a00 = __builtin_amdgcn_mfma_f32_16x16x32_bf16(av0, bfrag[kt][0],     a00, 0, 0, 0);
      a10 = __builtin_amdgcn_mfma_f32_16x16x32_bf16(av0, bfrag[kt][1],     a10, 0, 0, 0);
      a01 = __builtin_amdgcn_mfma_f32_16x16x32_bf16(av1, bfrag[kt + 1][0], a01, 0, 0, 0);
      a11 = __builtin_amdgcn_mfma_f32_16x16x32_bf16(av1, bfrag[kt + 1][1], a11, 0, 0, 0);
    }
    f32x4 acc0 = a00 + a01, acc1 = a10 + a11;

    // [C] z -> LDS
#pragma unroll
    for (int ri = 0; ri < 4; ++ri) {
      z_buf[wm * 16 + l4 * 4 + ri][wn * 32 + l15]      = acc0[ri];
      z_buf[wm * 16 + l4 * 4 + ri][wn * 32 + 16 + l15] = acc1[ri];
    }
    __syncthreads();  // [D]

    // [E] gate update (thread owns (bb, u2..u2+1))
    int lab = lab_lds[bb * NT + s];
    float hv[2];
#pragma unroll
    for (int q = 0; q < 2; ++q) {
      int u = u2 + q;
      float zi = z_buf[bb][u]      + wx_lds[lab][u];
      float zf = z_buf[bb][16 + u] + wx_lds[lab][16 + u];
      float zg = z_buf[bb][32 + u] + wx_lds[lab][32 + u];
      float zo = z_buf[bb][48 + u] + wx_lds[lab][48 + u];
      float cc = sigf(zf) * c_lds[bb][u] + sigf(zi) * tanhfast(zg);
      c_lds[bb][u] = cc;
      hv[q] = sigf(zo) * tanhfast(cc);
    }
    u32 pkv = pk2(hv[0], hv[1]);

    // [F] publish own slice to slot s+1 (device scope; monotonic slots)
    __hip_atomic_store(hbuf + (size_t)(s + 1) * 8192 + bb * 256 + ci, pkv,
                       __ATOMIC_RELAXED, __HIP_MEMORY_SCOPE_AGENT);

    // [G] own stores acked at coherence point, whole wg done
    asm volatile("s_waitcnt vmcnt(0)" ::: "memory");
    __syncthreads();   // also fences z_buf read (E) vs next write (C)

    // [H] arrive
    if (tid == 0)
      __hip_atomic_store(flags + g, (u32)(s + 1),
                         __ATOMIC_RELAXED, __HIP_MEMORY_SCOPE_AGENT);

    if (s == NT - 1) break;   // h_64 published+flagged for d1; recurrence done

    // [J] depart: poll all 32 flags, one coalesced load per wave
    {
      const u32 target = (u32)(s + 1);
      int guard = 0;
      for (;;) {
        u32 f = target;
        if (lane < NWG)
          f = __hip_atomic_load(flags + lane, __ATOMIC_RELAXED,
                                __HIP_MEMORY_SCOPE_AGENT);
        if (__all(f >= target)) break;
        if (++guard > 300000) break;   // anti-hang; break => visible absmax fail
        __builtin_amdgcn_s_sleep(1);
      }
    }

    // [K] 16 independent bypass loads of slot s+1 -> next A-fragments.
    {
      const u32* ap = hbuf + (size_t)(s + 1) * 8192 + arow * 256 + l4 * 4;
      LOAD_HSLOT(afrag, ap);
    }
  }
}

// ---------------------------------------------------------------------------
// score+softmax: one wave per (b,t); softmax over lanes; store out[b][s][t].
// ---------------------------------------------------------------------------
__global__ __launch_bounds__(256, 1)
void score_kernel(const unsigned short* __restrict__ d1_bf,
                  const unsigned short* __restrict__ e2_bf,
                  const float* __restrict__ V,
                  float* __restrict__ out)
{
  const int tid = threadIdx.x;
  const int wave = tid >> 6, lane = tid & 63;
  const int p = blockIdx.x * 4 + wave;   // 0..2047
  const int bb = p >> 6, t = p & 63;

  union { uint4 q; unsigned short us[8]; } dv;
  dv.q = *reinterpret_cast<const uint4*>(d1_bf + (bb * 64 + t) * NU + lane * 8);
  float d1f[8], Vf[8];
#pragma unroll
  for (int e = 0; e < 8; ++e) { d1f[e] = bf2f(dv.us[e]); Vf[e] = V[lane * 8 + e]; }

  float sc = 0.f;
  for (int s = 0; s < NS; ++s) {
    union { uint4 q; unsigned short us[8]; } ev;
    ev.q = *reinterpret_cast<const uint4*>(e2_bf + (bb * 64 + s) * NU + lane * 8);
    float part = 0.f;
#pragma unroll
    for (int e = 0; e < 8; ++e) part += tanhfast(d1f[e] + bf2f(ev.us[e])) * Vf[e];
#pragma unroll
    for (int o = 32; o > 0; o >>= 1) part += __shfl_xor(part, o);
    sc = (lane == s) ? part : sc;
  }
  float m = sc;
#pragma unroll
  for (int o = 32; o > 0; o >>= 1) m = fmaxf(m, __shfl_xor(m, o));
  float ex = __expf(sc - m);
  float sum = ex;
#pragma unroll
  for (int o = 32; o > 0; o >>= 1) sum += __shfl_xor(sum, o);
  out[(bb * 64 + lane) * 64 + t] = ex / sum;
}

// ---------------------------------------------------------------------------
extern "C" void kernel_launch(void* const* d_in, const int* in_sizes, int n_in,
                              void* d_out, int out_size, void* d_ws, size_t ws_size,
                              hipStream_t stream)
{
  (void)in_sizes; (void)n_in; (void)out_size;
  const int*   labels = (const int*)  d_in[0];
  const float* enc    = (const float*)d_in[1];
  const float* h0     = (const float*)d_in[2];
  const float* c0     = (const float*)d_in[3];
  const float* Wx     = (const float*)d_in[4];
  const float* Wh     = (const float*)d_in[5];
  const float* bias   = (const float*)d_in[6];
  const float* W1     = (const float*)d_in[7];
  const float* b1     = (const float*)d_in[8];
  const float* W2     = (const float*)d_in[9];
  const float* b2     = (const float*)d_in[10];
  const float* V      = (const float*)d_in[11];
  // d_in[12] = bv: additive scalar on all scores -> softmax-invariant.

  char* ws = (char*)d_ws;
  const size_t OFS_HB  = 32768;                          // flags before
  const size_t HB_SZ   = (size_t)65 * 8192 * 4;          // 65 slots x 32KB
  const size_t OFS_D1  = OFS_HB + HB_SZ;                 // 2MB
  const size_t OFS_E2  = OFS_D1 + (2u << 20);            // 2MB
  if (ws_size < OFS_E2 + (2u << 20)) return;             // ~6.4MB needed

  u32* flags = (u32*)(ws);
  u32* hbuf  = (u32*)(ws + OFS_HB);
  unsigned short* d1_bf = (unsigned short*)(ws + OFS_D1);
  unsigned short* e2_bf = (unsigned short*)(ws + OFS_E2);
  float* out = (float*)d_out;

  hipMemsetAsync(flags, 0, 256, stream);
  lstm_kernel<<<dim3(64), dim3(256), 0, stream>>>(labels, h0, c0, Wx, Wh, bias,
                                                  enc, W2, b2, W1, b1,
                                                  hbuf, flags, d1_bf, e2_bf);
  score_kernel<<<dim3(512), dim3(256), 0, stream>>>(d1_bf, e2_bf, V, out);
}

// Round 14
// 365.265 us; speedup vs baseline: 1.0412x; 1.0412x over previous
//
#include <hip/hip_runtime.h>
#include <hip/hip_bf16.h>

// Decoder: one-hot@Wx gather -> 64-step LSTM -> Bahdanau attention softmax.
// B=32, T=64, S=64, U=512, 4U=2048, VOCAB=65.
//
// Round 14: t-major post-recurrence d1. r13's pipelined col-split d1 cost
// ~27us of recurrence interference (polls + 64MB of redundant h slot reads:
// every one of 32 wgs re-read the full h_t). Now: (1) prep kernel (replaces
// memset dispatch; flags-clear folded in) pre-transposes W1 into w1bf =
// MFMA-fragment-major bf16 (1 frag = 1KB coalesced block); inter-kernel
// coherence is a HIP guarantee, no cache-scope bets (r8/r9 lesson).
// (2) mega: recurrence runs with ZERO d1 activity (e2 wgs wait with 1-wave
// sleep(127) polls); after all flags==64, all 64 wgs each do d1 for ONE
// timestep t=g+1: A = h_t loaded once (2 LOAD_HSLOT RTs), B = plain cached
// loads from w1bf, 256 MFMA. d1 wall ~6-10us, h traffic 8MB (8x less).

#define NB 32
#define NT 64
#define NS 64
#define NU 512
#define N4U 2048
#define NV 65
#define NWG 32

typedef unsigned int u32;
typedef __bf16 bf16_t;
typedef bf16_t bf16x8 __attribute__((ext_vector_type(8)));
typedef float f32x4 __attribute__((ext_vector_type(4)));
typedef u32 u32x4 __attribute__((ext_vector_type(4)));

__device__ __forceinline__ unsigned short f2bf(float f) {
  u32 u = __builtin_bit_cast(u32, f);
  u += 0x7fffu + ((u >> 16) & 1u);   // round-to-nearest-even
  return (unsigned short)(u >> 16);
}
__device__ __forceinline__ float bf2f(unsigned short s) {
  return __builtin_bit_cast(float, (u32)s << 16);
}
__device__ __forceinline__ u32 pk2(float a, float b) {
  return (u32)f2bf(a) | ((u32)f2bf(b) << 16);
}
__device__ __forceinline__ float sigf(float x) { return 1.0f / (1.0f + __expf(-x)); }
__device__ __forceinline__ float tanhfast(float x) {
  float e = __expf(2.0f * x);
  return 1.0f - 2.0f / (e + 1.0f);
}

// 16 slot-loads (sc0 sc1, L1-bypassing) -> A-fragments, waited IN-BLOCK.
#define LOAD_HSLOT(DST, AP)                                                   \
  asm volatile(                                                               \
    "global_load_dwordx4 %0, %16, off sc0 sc1\n\t"                            \
    "global_load_dwordx4 %1, %16, off offset:64 sc0 sc1\n\t"                  \
    "global_load_dwordx4 %2, %16, off offset:128 sc0 sc1\n\t"                 \
    "global_load_dwordx4 %3, %16, off offset:192 sc0 sc1\n\t"                 \
    "global_load_dwordx4 %4, %16, off offset:256 sc0 sc1\n\t"                 \
    "global_load_dwordx4 %5, %16, off offset:320 sc0 sc1\n\t"                 \
    "global_load_dwordx4 %6, %16, off offset:384 sc0 sc1\n\t"                 \
    "global_load_dwordx4 %7, %16, off offset:448 sc0 sc1\n\t"                 \
    "global_load_dwordx4 %8, %16, off offset:512 sc0 sc1\n\t"                 \
    "global_load_dwordx4 %9, %16, off offset:576 sc0 sc1\n\t"                 \
    "global_load_dwordx4 %10, %16, off offset:640 sc0 sc1\n\t"                \
    "global_load_dwordx4 %11, %16, off offset:704 sc0 sc1\n\t"                \
    "global_load_dwordx4 %12, %16, off offset:768 sc0 sc1\n\t"                \
    "global_load_dwordx4 %13, %16, off offset:832 sc0 sc1\n\t"                \
    "global_load_dwordx4 %14, %16, off offset:896 sc0 sc1\n\t"                \
    "global_load_dwordx4 %15, %16, off offset:960 sc0 sc1\n\t"                \
    "s_waitcnt vmcnt(0)"                                                      \
    : "=&v"(DST[0]),  "=&v"(DST[1]),  "=&v"(DST[2]),  "=&v"(DST[3]),          \
      "=&v"(DST[4]),  "=&v"(DST[5]),  "=&v"(DST[6]),  "=&v"(DST[7]),          \
      "=&v"(DST[8]),  "=&v"(DST[9]),  "=&v"(DST[10]), "=&v"(DST[11]),         \
      "=&v"(DST[12]), "=&v"(DST[13]), "=&v"(DST[14]), "=&v"(DST[15])          \
    : "v"(AP)                                                                 \
    : "memory")

// ---------------------------------------------------------------------------
// prep: clear flags + transpose W1 f32 -> w1bf fragment-major bf16.
// Fragment (kt, c16): unit base = (kt*32+c16)*512; within: l15*32 + l4*8 + e
// holds W1[kt*32 + l4*8 + e][c16*16 + l15]. One frag = 1KB contiguous.
// grid 32 x 256; each wg converts 8192 elems (32/thread, coalesced writes).
// ---------------------------------------------------------------------------
__global__ __launch_bounds__(256, 1)
void prep_kernel(const float* __restrict__ W1,
                 unsigned short* __restrict__ w1bf,
                 u32* __restrict__ flags)
{
  const int tid = threadIdx.x, g = blockIdx.x;
  if (g == 0 && tid < 64) flags[tid] = 0;
  int i0 = g * 8192 + tid;
#pragma unroll
  for (int j = 0; j < 32; ++j) {
    int i = i0 + j * 256;
    int e   = i & 7;
    int l4  = (i >> 3) & 3;
    int l15 = (i >> 5) & 15;
    int c16 = (i >> 9) & 31;
    int kt  = (i >> 14) & 15;
    int k   = kt * 32 + l4 * 8 + e;
    int col = c16 * 16 + l15;
    w1bf[i] = f2bf(W1[k * NU + col]);
  }
}

// ---------------------------------------------------------------------------
// Mega kernel, grid 64 x 256.
//   wgs 0..31:  LSTM recurrence (wg g owns h units [g*16,g*16+16)), then d1.
//   wgs 32..63: e2 = enc@W2+b2, lazy wait for flags==64, then d1.
//   d1 phase (all wgs): wg g computes d1 rows for t = g+1 (all 32 b, 512 c).
// hbuf: [65 slots][32][256] u32 bf16-pairs. flags: [32], cleared by prep.
// ---------------------------------------------------------------------------
__global__ __launch_bounds__(256, 1)
void lstm_kernel(const int* __restrict__ labels,
                 const float* __restrict__ h0,
                 const float* __restrict__ c0,
                 const float* __restrict__ Wx,
                 const float* __restrict__ Wh,
                 const float* __restrict__ bias,
                 const float* __restrict__ enc,
                 const float* __restrict__ W2,
                 const float* __restrict__ b2,
                 const unsigned short* __restrict__ w1bf,
                 const float* __restrict__ b1,
                 u32* __restrict__ hbuf,    // [65][32][256] bf16-pairs
                 u32* __restrict__ flags,   // [32] per-wg epoch (prep-cleared)
                 unsigned short* __restrict__ d1_bf,
                 unsigned short* __restrict__ e2_bf)
{
  __shared__ float z_buf[NB][65];            // padded: conflict-free gate reads
  __shared__ float c_lds[NB][16];
  __shared__ float wx_lds[NV][65];           // Wx slice + bias folded, padded
  __shared__ unsigned char lab_lds[NB * NT]; // labels cached (values < 65)

  const int tid  = threadIdx.x;
  const int g    = blockIdx.x;
  const int wave = tid >> 6, lane = tid & 63;
  const int l15  = lane & 15, l4 = lane >> 4;

  if (g >= NWG) {
    // ------------------------ e2 wgs (32..63) ------------------------------
    const int r0 = (g - NWG) * 64 + wave * 16;   // 16 rows per wave
    const int arowE = r0 + l15;
    u32x4 afragE[16];
#pragma unroll
    for (int kt = 0; kt < 16; ++kt) {
      const float* ep = enc + arowE * NU + kt * 32 + l4 * 8;
      u32x4 t;
      t.x = pk2(ep[0], ep[1]); t.y = pk2(ep[2], ep[3]);
      t.z = pk2(ep[4], ep[5]); t.w = pk2(ep[6], ep[7]);
      afragE[kt] = t;
    }
    for (int cg = 0; cg < 8; ++cg) {
      f32x4 acc[4] = {};
      for (int kt = 0; kt < 16; ++kt) {
        bf16x8 a = __builtin_bit_cast(bf16x8, afragE[kt]);
        int k0 = kt * 32 + l4 * 8;
#pragma unroll
        for (int nt = 0; nt < 4; ++nt) {
          int col = cg * 64 + nt * 16 + l15;
          union { unsigned short us[8]; bf16x8 v; } bu;
#pragma unroll
          for (int e = 0; e < 8; ++e) bu.us[e] = f2bf(W2[(k0 + e) * NU + col]);
          acc[nt] = __builtin_amdgcn_mfma_f32_16x16x32_bf16(a, bu.v, acc[nt], 0, 0, 0);
        }
      }
#pragma unroll
      for (int nt = 0; nt < 4; ++nt) {
        int col = cg * 64 + nt * 16 + l15;
        float bc = b2[col];
#pragma unroll
        for (int ri = 0; ri < 4; ++ri)
          e2_bf[(r0 + l4 * 4 + ri) * NU + col] = f2bf(acc[nt][ri] + bc);
      }
    }
    // lazy wait for recurrence completion: ONLY wave 0 polls (sleep ~3.4us);
    // other waves park in the barrier below (zero memory traffic).
    if (wave == 0) {
      int guard = 0;
      for (;;) {
        u32 f = 64;
        if (lane < NWG)
          f = __hip_atomic_load(flags + lane, __ATOMIC_RELAXED,
                                __HIP_MEMORY_SCOPE_AGENT);
        if (__all(f >= 64u)) break;
        if (++guard > 150000) break;   // anti-hang (~0.5s) => absmax fail
        __builtin_amdgcn_s_sleep(127);
      }
    }
  } else {
    // ------------------------ LSTM wgs (0..31) -----------------------------
    const int wm = wave >> 1, wn = wave & 1;

    for (int i = tid; i < NV * 64; i += 256) {
      int v = i >> 6, c = i & 63;
      int j = (c >> 4) * NU + g * 16 + (c & 15);
      wx_lds[v][c] = Wx[v * N4U + j] + bias[j];
    }
    for (int i = tid; i < NB * 16; i += 256) {
      int r = i >> 4, u = i & 15;
      c_lds[r][u] = c0[r * NU + g * 16 + u];
    }
    for (int i = tid; i < NB * NT; i += 256) lab_lds[i] = (unsigned char)labels[i];

    // Wh B-fragments -> VGPRs, once (layout validated r1-r13).
    bf16x8 bfrag[16][2];
#pragma unroll
    for (int kt = 0; kt < 16; ++kt) {
#pragma unroll
      for (int nt = 0; nt < 2; ++nt) {
        int c = wn * 32 + nt * 16 + l15;
        int j = (c >> 4) * NU + g * 16 + (c & 15);
        int kb = kt * 32 + l4 * 8;
        union { unsigned short us[8]; bf16x8 v; } bu;
#pragma unroll
        for (int e = 0; e < 8; ++e) bu.us[e] = f2bf(Wh[(kb + e) * N4U + j]);
        bfrag[kt][nt] = bu.v;
      }
    }

    // A-fragments from h0.
    const int arow = wm * 16 + l15;
    u32x4 afrag[16];
#pragma unroll
    for (int kt = 0; kt < 16; ++kt) {
      const float* hp = h0 + arow * NU + kt * 32 + l4 * 8;
      u32x4 t;
      t.x = pk2(hp[0], hp[1]); t.y = pk2(hp[2], hp[3]);
      t.z = pk2(hp[4], hp[5]); t.w = pk2(hp[6], hp[7]);
      afrag[kt] = t;
    }

    const int bb = tid >> 3;          // batch handled in update phase
    const int u2 = (tid & 7) * 2;     // unit pair
    const int ci = g * 8 + (tid & 7); // u32 col in [32][256] h layout

    for (int s = 0; s < NT; ++s) {
      // [B] z = h @ WhSlice  (4 chains)
      f32x4 a00 = {0.f,0.f,0.f,0.f}, a01 = a00, a10 = a00, a11 = a00;
#pragma unroll
      for (int kt = 0; kt < 16; kt += 2) {
        bf16x8 av0 = __builtin_bit_cast(bf16x8, afrag[kt]);
        bf16x8 av1 = __builtin_bit_cast(bf16x8, afrag[kt + 1]);
        a00 = __builtin_amdgcn_mfma_f32_16x16x32_bf16(av0, bfrag[kt][0],     a00, 0, 0, 0);
        a10 = __builtin_amdgcn_mfma_f32_16x16x32_bf16(av0, bfrag[kt][1],     a10, 0, 0, 0);
        a01 = __builtin_amdgcn_mfma_f32_16x16x32_bf16(av1, bfrag[kt + 1][0], a01, 0, 0, 0);
        a11 = __builtin_amdgcn_mfma_f32_16x16x32_bf16(av1, bfrag[kt + 1][1], a11, 0, 0, 0);
      }
      f32x4 acc0 = a00 + a01, acc1 = a10 + a11;

      // [C] z -> LDS
#pragma unroll
      for (int ri = 0; ri < 4; ++ri) {
        z_buf[wm * 16 + l4 * 4 + ri][wn * 32 + l15]      = acc0[ri];
        z_buf[wm * 16 + l4 * 4 + ri][wn * 32 + 16 + l15] = acc1[ri];
      }
      __syncthreads();  // [D]

      // [E] gate update
      int lab = lab_lds[bb * NT + s];
      float hv[2];
#pragma unroll
      for (int q = 0; q < 2; ++q) {
        int u = u2 + q;
        float zi = z_buf[bb][u]      + wx_lds[lab][u];
        float zf = z_buf[bb][16 + u] + wx_lds[lab][16 + u];
        float zg = z_buf[bb][32 + u] + wx_lds[lab][32 + u];
        float zo = z_buf[bb][48 + u] + wx_lds[lab][48 + u];
        float cc = sigf(zf) * c_lds[bb][u] + sigf(zi) * tanhfast(zg);
        c_lds[bb][u] = cc;
        hv[q] = sigf(zo) * tanhfast(cc);
      }
      u32 pkv = pk2(hv[0], hv[1]);

      // [F] publish own slice to slot s+1 (device scope; monotonic slots)
      __hip_atomic_store(hbuf + (size_t)(s + 1) * 8192 + bb * 256 + ci, pkv,
                         __ATOMIC_RELAXED, __HIP_MEMORY_SCOPE_AGENT);

      // [G] own stores acked, whole wg done
      asm volatile("s_waitcnt vmcnt(0)" ::: "memory");
      __syncthreads();

      // [H] arrive
      if (tid == 0)
        __hip_atomic_store(flags + g, (u32)(s + 1),
                           __ATOMIC_RELAXED, __HIP_MEMORY_SCOPE_AGENT);

      if (s == NT - 1) break;   // h_64 published+flagged; recurrence done

      // [J] depart: poll all 32 flags
      {
        const u32 target = (u32)(s + 1);
        int guard = 0;
        for (;;) {
          u32 f = target;
          if (lane < NWG)
            f = __hip_atomic_load(flags + lane, __ATOMIC_RELAXED,
                                  __HIP_MEMORY_SCOPE_AGENT);
          if (__all(f >= target)) break;
          if (++guard > 300000) break;   // anti-hang => visible absmax fail
          __builtin_amdgcn_s_sleep(1);
        }
      }

      // [K] 16 bypass loads of slot s+1 -> next A-fragments.
      {
        const u32* ap = hbuf + (size_t)(s + 1) * 8192 + arow * 256 + l4 * 4;
        LOAD_HSLOT(afrag, ap);
      }
    }

    // quick wait for the remaining wgs to reach step 64 (wave 0 only)
    if (wave == 0) {
      int guard = 0;
      for (;;) {
        u32 f = 64;
        if (lane < NWG)
          f = __hip_atomic_load(flags + lane, __ATOMIC_RELAXED,
                                __HIP_MEMORY_SCOPE_AGENT);
        if (__all(f >= 64u)) break;
        if (++guard > 500000) break;   // anti-hang => visible absmax fail
        __builtin_amdgcn_s_sleep(1);
      }
    }
  }

  __syncthreads();   // all waves of this wg: recurrence fully complete

  // --------------------- d1 phase: wg g owns t = g+1 -----------------------
  // d1[b, t-1, col] = h_t[b,:] @ W1[:,col] + b1[col], b=0..31, col=0..511.
  // Wave v covers cols [v*128, v*128+128). A (h_t) loaded once: 32 frags.
  {
    const int t = g + 1;
    u32x4 A0[16], A1[16];
    const u32* ap0 = hbuf + (size_t)t * 8192 + l15 * 256 + l4 * 4;        // b 0..15
    const u32* ap1 = hbuf + (size_t)t * 8192 + (16 + l15) * 256 + l4 * 4; // b 16..31
    LOAD_HSLOT(A0, ap0);
    LOAD_HSLOT(A1, ap1);

#pragma unroll
    for (int cg = 0; cg < 8; ++cg) {
      const int c16 = wave * 8 + cg;
      f32x4 acc0 = {0.f, 0.f, 0.f, 0.f}, acc1 = acc0;
#pragma unroll
      for (int kt = 0; kt < 16; ++kt) {
        uint4 braw = *reinterpret_cast<const uint4*>(
            w1bf + ((kt * 32 + c16) * 512 + l15 * 32 + l4 * 8));
        bf16x8 b = __builtin_bit_cast(bf16x8, braw);
        acc0 = __builtin_amdgcn_mfma_f32_16x16x32_bf16(
                 __builtin_bit_cast(bf16x8, A0[kt]), b, acc0, 0, 0, 0);
        acc1 = __builtin_amdgcn_mfma_f32_16x16x32_bf16(
                 __builtin_bit_cast(bf16x8, A1[kt]), b, acc1, 0, 0, 0);
      }
      const int col = c16 * 16 + l15;
      const float bc = b1[col];
#pragma unroll
      for (int ri = 0; ri < 4; ++ri) {
        int b0 = l4 * 4 + ri;
        d1_bf[((b0)      * NT + (t - 1)) * NU + col] = f2bf(acc0[ri] + bc);
        d1_bf[((b0 + 16) * NT + (t - 1)) * NU + col] = f2bf(acc1[ri] + bc);
      }
    }
  }
}

// ---------------------------------------------------------------------------
// score+softmax: one wave per (b,t); softmax over lanes; store out[b][s][t].
// ---------------------------------------------------------------------------
__global__ __launch_bounds__(256, 1)
void score_kernel(const unsigned short* __restrict__ d1_bf,
                  const unsigned short* __restrict__ e2_bf,
                  const float* __restrict__ V,
                  float* __restrict__ out)
{
  const int tid = threadIdx.x;
  const int wave = tid >> 6, lane = tid & 63;
  const int p = blockIdx.x * 4 + wave;   // 0..2047
  const int bb = p >> 6, t = p & 63;

  union { uint4 q; unsigned short us[8]; } dv;
  dv.q = *reinterpret_cast<const uint4*>(d1_bf + (bb * 64 + t) * NU + lane * 8);
  float d1f[8], Vf[8];
#pragma unroll
  for (int e = 0; e < 8; ++e) { d1f[e] = bf2f(dv.us[e]); Vf[e] = V[lane * 8 + e]; }

  float sc = 0.f;
  for (int s = 0; s < NS; ++s) {
    union { uint4 q; unsigned short us[8]; } ev;
    ev.q = *reinterpret_cast<const uint4*>(e2_bf + (bb * 64 + s) * NU + lane * 8);
    float part = 0.f;
#pragma unroll
    for (int e = 0; e < 8; ++e) part += tanhfast(d1f[e] + bf2f(ev.us[e])) * Vf[e];
#pragma unroll
    for (int o = 32; o > 0; o >>= 1) part += __shfl_xor(part, o);
    sc = (lane == s) ? part : sc;
  }
  float m = sc;
#pragma unroll
  for (int o = 32; o > 0; o >>= 1) m = fmaxf(m, __shfl_xor(m, o));
  float ex = __expf(sc - m);
  float sum = ex;
#pragma unroll
  for (int o = 32; o > 0; o >>= 1) sum += __shfl_xor(sum, o);
  out[(bb * 64 + lane) * 64 + t] = ex / sum;
}

// ---------------------------------------------------------------------------
extern "C" void kernel_launch(void* const* d_in, const int* in_sizes, int n_in,
                              void* d_out, int out_size, void* d_ws, size_t ws_size,
                              hipStream_t stream)
{
  (void)in_sizes; (void)n_in; (void)out_size;
  const int*   labels = (const int*)  d_in[0];
  const float* enc    = (const float*)d_in[1];
  const float* h0     = (const float*)d_in[2];
  const float* c0     = (const float*)d_in[3];
  const float* Wx     = (const float*)d_in[4];
  const float* Wh     = (const float*)d_in[5];
  const float* bias   = (const float*)d_in[6];
  const float* W1     = (const float*)d_in[7];
  const float* b1     = (const float*)d_in[8];
  const float* W2     = (const float*)d_in[9];
  const float* b2     = (const float*)d_in[10];
  const float* V      = (const float*)d_in[11];
  // d_in[12] = bv: additive scalar on all scores -> softmax-invariant.

  char* ws = (char*)d_ws;
  const size_t OFS_W1B = 4096;                           // 512KB w1bf
  const size_t OFS_HB  = OFS_W1B + 524288;               // 65 x 32KB hbuf
  const size_t OFS_D1  = OFS_HB + (size_t)65 * 32768;    // 2MB d1
  const size_t OFS_E2  = OFS_D1 + (2u << 20);            // 2MB e2
  if (ws_size < OFS_E2 + (2u << 20)) return;             // ~6.9MB needed

  u32* flags = (u32*)(ws);
  unsigned short* w1bf = (unsigned short*)(ws + OFS_W1B);
  u32* hbuf  = (u32*)(ws + OFS_HB);
  unsigned short* d1_bf = (unsigned short*)(ws + OFS_D1);
  unsigned short* e2_bf = (unsigned short*)(ws + OFS_E2);
  float* out = (float*)d_out;

  prep_kernel<<<dim3(32), dim3(256), 0, stream>>>(W1, w1bf, flags);
  lstm_kernel<<<dim3(64), dim3(256), 0, stream>>>(labels, h0, c0, Wx, Wh, bias,
                                                  enc, W2, b2, w1bf, b1,
                                                  hbuf, flags, d1_bf, e2_bf);
  score_kernel<<<dim3(512), dim3(256), 0, stream>>>(d1_bf, e2_bf, V, out);
}

// Round 16
// 365.034 us; speedup vs baseline: 1.0418x; 1.0006x over previous
//
#include <hip/hip_runtime.h>
#include <hip/hip_bf16.h>

// Decoder: one-hot@Wx gather -> 64-step LSTM -> Bahdanau attention softmax.
// B=32, T=64, S=64, U=512, 4U=2048, VOCAB=65.
//
// Round 16: REVERT to r14 (last known-good, 365us, replay-stable).
// r15's d1 micro-cleanup (1-RT A-fetch + LDS-staged t-major writes) gained
// 0us AND introduced a replay-only divergence -> the d1 tail is SKEW-bound
// (slowest recurrence wg), not RT/coalescing-bound. Final structure:
//  - prep: W1 -> fragment-major bf16 (w1bf) + flags clear.
//  - mega: wgs 0..31 recurrence (4.93us/step = measured optimum over 7
//    protocol variants; ~4 device-scope RTs/step irreducible at HIP level;
//    intra-XCD L2 exchange refuted twice r8/r9); wgs 32..63 e2 then lazy
//    wait; all 64 wgs then d1 for one timestep each.
//  - score: per-wave softmax.
// This is a latency floor (MfmaUtil ~0.7%, HBM ~1%), not a HW roofline:
// the binding resource is MALL RT latency x 256 serial exchanges.

#define NB 32
#define NT 64
#define NS 64
#define NU 512
#define N4U 2048
#define NV 65
#define NWG 32

typedef unsigned int u32;
typedef __bf16 bf16_t;
typedef bf16_t bf16x8 __attribute__((ext_vector_type(8)));
typedef float f32x4 __attribute__((ext_vector_type(4)));
typedef u32 u32x4 __attribute__((ext_vector_type(4)));

__device__ __forceinline__ unsigned short f2bf(float f) {
  u32 u = __builtin_bit_cast(u32, f);
  u += 0x7fffu + ((u >> 16) & 1u);   // round-to-nearest-even
  return (unsigned short)(u >> 16);
}
__device__ __forceinline__ float bf2f(unsigned short s) {
  return __builtin_bit_cast(float, (u32)s << 16);
}
__device__ __forceinline__ u32 pk2(float a, float b) {
  return (u32)f2bf(a) | ((u32)f2bf(b) << 16);
}
__device__ __forceinline__ float sigf(float x) { return 1.0f / (1.0f + __expf(-x)); }
__device__ __forceinline__ float tanhfast(float x) {
  float e = __expf(2.0f * x);
  return 1.0f - 2.0f / (e + 1.0f);
}

// 16 slot-loads (sc0 sc1, L1-bypassing) -> A-fragments, waited IN-BLOCK.
#define LOAD_HSLOT(DST, AP)                                                   \
  asm volatile(                                                               \
    "global_load_dwordx4 %0, %16, off sc0 sc1\n\t"                            \
    "global_load_dwordx4 %1, %16, off offset:64 sc0 sc1\n\t"                  \
    "global_load_dwordx4 %2, %16, off offset:128 sc0 sc1\n\t"                 \
    "global_load_dwordx4 %3, %16, off offset:192 sc0 sc1\n\t"                 \
    "global_load_dwordx4 %4, %16, off offset:256 sc0 sc1\n\t"                 \
    "global_load_dwordx4 %5, %16, off offset:320 sc0 sc1\n\t"                 \
    "global_load_dwordx4 %6, %16, off offset:384 sc0 sc1\n\t"                 \
    "global_load_dwordx4 %7, %16, off offset:448 sc0 sc1\n\t"                 \
    "global_load_dwordx4 %8, %16, off offset:512 sc0 sc1\n\t"                 \
    "global_load_dwordx4 %9, %16, off offset:576 sc0 sc1\n\t"                 \
    "global_load_dwordx4 %10, %16, off offset:640 sc0 sc1\n\t"                \
    "global_load_dwordx4 %11, %16, off offset:704 sc0 sc1\n\t"                \
    "global_load_dwordx4 %12, %16, off offset:768 sc0 sc1\n\t"                \
    "global_load_dwordx4 %13, %16, off offset:832 sc0 sc1\n\t"                \
    "global_load_dwordx4 %14, %16, off offset:896 sc0 sc1\n\t"                \
    "global_load_dwordx4 %15, %16, off offset:960 sc0 sc1\n\t"                \
    "s_waitcnt vmcnt(0)"                                                      \
    : "=&v"(DST[0]),  "=&v"(DST[1]),  "=&v"(DST[2]),  "=&v"(DST[3]),          \
      "=&v"(DST[4]),  "=&v"(DST[5]),  "=&v"(DST[6]),  "=&v"(DST[7]),          \
      "=&v"(DST[8]),  "=&v"(DST[9]),  "=&v"(DST[10]), "=&v"(DST[11]),         \
      "=&v"(DST[12]), "=&v"(DST[13]), "=&v"(DST[14]), "=&v"(DST[15])          \
    : "v"(AP)                                                                 \
    : "memory")

// ---------------------------------------------------------------------------
// prep: clear flags + transpose W1 f32 -> w1bf fragment-major bf16.
// Fragment (kt, c16): base (kt*32+c16)*512; entry l15*32+l4*8+e holds
// W1[kt*32+l4*8+e][c16*16+l15]. One frag = 1KB contiguous.
// ---------------------------------------------------------------------------
__global__ __launch_bounds__(256, 1)
void prep_kernel(const float* __restrict__ W1,
                 unsigned short* __restrict__ w1bf,
                 u32* __restrict__ flags)
{
  const int tid = threadIdx.x, g = blockIdx.x;
  if (g == 0 && tid < 64) flags[tid] = 0;
  int i0 = g * 8192 + tid;
#pragma unroll
  for (int j = 0; j < 32; ++j) {
    int i = i0 + j * 256;
    int e   = i & 7;
    int l4  = (i >> 3) & 3;
    int l15 = (i >> 5) & 15;
    int c16 = (i >> 9) & 31;
    int kt  = (i >> 14) & 15;
    w1bf[i] = f2bf(W1[(kt * 32 + l4 * 8 + e) * NU + c16 * 16 + l15]);
  }
}

// ---------------------------------------------------------------------------
// Mega kernel, grid 64 x 256.
//   wgs 0..31:  LSTM recurrence (wg g owns h units [g*16,g*16+16)), then d1.
//   wgs 32..63: e2 = enc@W2+b2, lazy wait for flags==64, then d1.
//   d1 phase (all wgs): wg g computes d1 rows for t = g+1 (all 32 b, 512 c).
// hbuf: [65 slots][32][256] u32 bf16-pairs. flags: [32], cleared by prep.
// ---------------------------------------------------------------------------
__global__ __launch_bounds__(256, 1)
void lstm_kernel(const int* __restrict__ labels,
                 const float* __restrict__ h0,
                 const float* __restrict__ c0,
                 const float* __restrict__ Wx,
                 const float* __restrict__ Wh,
                 const float* __restrict__ bias,
                 const float* __restrict__ enc,
                 const float* __restrict__ W2,
                 const float* __restrict__ b2,
                 const unsigned short* __restrict__ w1bf,
                 const float* __restrict__ b1,
                 u32* __restrict__ hbuf,    // [65][32][256] bf16-pairs
                 u32* __restrict__ flags,   // [32] per-wg epoch (prep-cleared)
                 unsigned short* __restrict__ d1_bf,
                 unsigned short* __restrict__ e2_bf)
{
  __shared__ float z_buf[NB][65];            // padded: conflict-free gate reads
  __shared__ float c_lds[NB][16];
  __shared__ float wx_lds[NV][65];           // Wx slice + bias folded, padded
  __shared__ unsigned char lab_lds[NB * NT]; // labels cached (values < 65)

  const int tid  = threadIdx.x;
  const int g    = blockIdx.x;
  const int wave = tid >> 6, lane = tid & 63;
  const int l15  = lane & 15, l4 = lane >> 4;

  if (g >= NWG) {
    // ------------------------ e2 wgs (32..63) ------------------------------
    const int r0 = (g - NWG) * 64 + wave * 16;   // 16 rows per wave
    const int arowE = r0 + l15;
    u32x4 afragE[16];
#pragma unroll
    for (int kt = 0; kt < 16; ++kt) {
      const float* ep = enc + arowE * NU + kt * 32 + l4 * 8;
      u32x4 t;
      t.x = pk2(ep[0], ep[1]); t.y = pk2(ep[2], ep[3]);
      t.z = pk2(ep[4], ep[5]); t.w = pk2(ep[6], ep[7]);
      afragE[kt] = t;
    }
    for (int cg = 0; cg < 8; ++cg) {
      f32x4 acc[4] = {};
      for (int kt = 0; kt < 16; ++kt) {
        bf16x8 a = __builtin_bit_cast(bf16x8, afragE[kt]);
        int k0 = kt * 32 + l4 * 8;
#pragma unroll
        for (int nt = 0; nt < 4; ++nt) {
          int col = cg * 64 + nt * 16 + l15;
          union { unsigned short us[8]; bf16x8 v; } bu;
#pragma unroll
          for (int e = 0; e < 8; ++e) bu.us[e] = f2bf(W2[(k0 + e) * NU + col]);
          acc[nt] = __builtin_amdgcn_mfma_f32_16x16x32_bf16(a, bu.v, acc[nt], 0, 0, 0);
        }
      }
#pragma unroll
      for (int nt = 0; nt < 4; ++nt) {
        int col = cg * 64 + nt * 16 + l15;
        float bc = b2[col];
#pragma unroll
        for (int ri = 0; ri < 4; ++ri)
          e2_bf[(r0 + l4 * 4 + ri) * NU + col] = f2bf(acc[nt][ri] + bc);
      }
    }
    // lazy wait for recurrence completion: ONLY wave 0 polls (sleep ~3.4us);
    // other waves park in the barrier below (zero memory traffic).
    if (wave == 0) {
      int guard = 0;
      for (;;) {
        u32 f = 64;
        if (lane < NWG)
          f = __hip_atomic_load(flags + lane, __ATOMIC_RELAXED,
                                __HIP_MEMORY_SCOPE_AGENT);
        if (__all(f >= 64u)) break;
        if (++guard > 150000) break;   // anti-hang (~0.5s) => absmax fail
        __builtin_amdgcn_s_sleep(127);
      }
    }
  } else {
    // ------------------------ LSTM wgs (0..31) -----------------------------
    const int wm = wave >> 1, wn = wave & 1;

    for (int i = tid; i < NV * 64; i += 256) {
      int v = i >> 6, c = i & 63;
      int j = (c >> 4) * NU + g * 16 + (c & 15);
      wx_lds[v][c] = Wx[v * N4U + j] + bias[j];
    }
    for (int i = tid; i < NB * 16; i += 256) {
      int r = i >> 4, u = i & 15;
      c_lds[r][u] = c0[r * NU + g * 16 + u];
    }
    for (int i = tid; i < NB * NT; i += 256) lab_lds[i] = (unsigned char)labels[i];

    // Wh B-fragments -> VGPRs, once (layout validated r1-r14).
    bf16x8 bfrag[16][2];
#pragma unroll
    for (int kt = 0; kt < 16; ++kt) {
#pragma unroll
      for (int nt = 0; nt < 2; ++nt) {
        int c = wn * 32 + nt * 16 + l15;
        int j = (c >> 4) * NU + g * 16 + (c & 15);
        int kb = kt * 32 + l4 * 8;
        union { unsigned short us[8]; bf16x8 v; } bu;
#pragma unroll
        for (int e = 0; e < 8; ++e) bu.us[e] = f2bf(Wh[(kb + e) * N4U + j]);
        bfrag[kt][nt] = bu.v;
      }
    }

    // A-fragments from h0.
    const int arow = wm * 16 + l15;
    u32x4 afrag[16];
#pragma unroll
    for (int kt = 0; kt < 16; ++kt) {
      const float* hp = h0 + arow * NU + kt * 32 + l4 * 8;
      u32x4 t;
      t.x = pk2(hp[0], hp[1]); t.y = pk2(hp[2], hp[3]);
      t.z = pk2(hp[4], hp[5]); t.w = pk2(hp[6], hp[7]);
      afrag[kt] = t;
    }

    const int bb = tid >> 3;          // batch handled in update phase
    const int u2 = (tid & 7) * 2;     // unit pair
    const int ci = g * 8 + (tid & 7); // u32 col in [32][256] h layout

    for (int s = 0; s < NT; ++s) {
      // [B] z = h @ WhSlice  (4 chains)
      f32x4 a00 = {0.f,0.f,0.f,0.f}, a01 = a00, a10 = a00, a11 = a00;
#pragma unroll
      for (int kt = 0; kt < 16; kt += 2) {
        bf16x8 av0 = __builtin_bit_cast(bf16x8, afrag[kt]);
        bf16x8 av1 = __builtin_bit_cast(bf16x8, afrag[kt + 1]);
        a00 = __builtin_amdgcn_mfma_f32_16x16x32_bf16(av0, bfrag[kt][0],     a00, 0, 0, 0);
        a10 = __builtin_amdgcn_mfma_f32_16x16x32_bf16(av0, bfrag[kt][1],     a10, 0, 0, 0);
        a01 = __builtin_amdgcn_mfma_f32_16x16x32_bf16(av1, bfrag[kt + 1][0], a01, 0, 0, 0);
        a11 = __builtin_amdgcn_mfma_f32_16x16x32_bf16(av1, bfrag[kt + 1][1], a11, 0, 0, 0);
      }
      f32x4 acc0 = a00 + a01, acc1 = a10 + a11;

      // [C] z -> LDS
#pragma unroll
      for (int ri = 0; ri < 4; ++ri) {
        z_buf[wm * 16 + l4 * 4 + ri][wn * 32 + l15]      = acc0[ri];
        z_buf[wm * 16 + l4 * 4 + ri][wn * 32 + 16 + l15] = acc1[ri];
      }
      __syncthreads();  // [D]

      // [E] gate update
      int lab = lab_lds[bb * NT + s];
      float hv[2];
#pragma unroll
      for (int q = 0; q < 2; ++q) {
        int u = u2 + q;
        float zi = z_buf[bb][u]      + wx_lds[lab][u];
        float zf = z_buf[bb][16 + u] + wx_lds[lab][16 + u];
        float zg = z_buf[bb][32 + u] + wx_lds[lab][32 + u];
        float zo = z_buf[bb][48 + u] + wx_lds[lab][48 + u];
        float cc = sigf(zf) * c_lds[bb][u] + sigf(zi) * tanhfast(zg);
        c_lds[bb][u] = cc;
        hv[q] = sigf(zo) * tanhfast(cc);
      }
      u32 pkv = pk2(hv[0], hv[1]);

      // [F] publish own slice to slot s+1 (device scope; monotonic slots)
      __hip_atomic_store(hbuf + (size_t)(s + 1) * 8192 + bb * 256 + ci, pkv,
                         __ATOMIC_RELAXED, __HIP_MEMORY_SCOPE_AGENT);

      // [G] own stores acked, whole wg done
      asm volatile("s_waitcnt vmcnt(0)" ::: "memory");
      __syncthreads();

      // [H] arrive
      if (tid == 0)
        __hip_atomic_store(flags + g, (u32)(s + 1),
                           __ATOMIC_RELAXED, __HIP_MEMORY_SCOPE_AGENT);

      if (s == NT - 1) break;   // h_64 published+flagged; recurrence done

      // [J] depart: poll all 32 flags
      {
        const u32 target = (u32)(s + 1);
        int guard = 0;
        for (;;) {
          u32 f = target;
          if (lane < NWG)
            f = __hip_atomic_load(flags + lane, __ATOMIC_RELAXED,
                                  __HIP_MEMORY_SCOPE_AGENT);
          if (__all(f >= target)) break;
          if (++guard > 300000) break;   // anti-hang => visible absmax fail
          __builtin_amdgcn_s_sleep(1);
        }
      }

      // [K] 16 bypass loads of slot s+1 -> next A-fragments.
      {
        const u32* ap = hbuf + (size_t)(s + 1) * 8192 + arow * 256 + l4 * 4;
        LOAD_HSLOT(afrag, ap);
      }
    }

    // quick wait for the remaining wgs to reach step 64 (wave 0 only)
    if (wave == 0) {
      int guard = 0;
      for (;;) {
        u32 f = 64;
        if (lane < NWG)
          f = __hip_atomic_load(flags + lane, __ATOMIC_RELAXED,
                                __HIP_MEMORY_SCOPE_AGENT);
        if (__all(f >= 64u)) break;
        if (++guard > 500000) break;   // anti-hang => visible absmax fail
        __builtin_amdgcn_s_sleep(1);
      }
    }
  }

  __syncthreads();   // all waves of this wg: recurrence fully complete

  // --------------------- d1 phase: wg g owns t = g+1 -----------------------
  // d1[b, t-1, col] = h_t[b,:] @ W1[:,col] + b1[col], b=0..31, col=0..511.
  // Wave v covers cols [v*128, v*128+128). A (h_t) loaded once: 32 frags.
  {
    const int t = g + 1;
    u32x4 A0[16], A1[16];
    const u32* ap0 = hbuf + (size_t)t * 8192 + l15 * 256 + l4 * 4;        // b 0..15
    const u32* ap1 = hbuf + (size_t)t * 8192 + (16 + l15) * 256 + l4 * 4; // b 16..31
    LOAD_HSLOT(A0, ap0);
    LOAD_HSLOT(A1, ap1);

#pragma unroll
    for (int cg = 0; cg < 8; ++cg) {
      const int c16 = wave * 8 + cg;
      f32x4 acc0 = {0.f, 0.f, 0.f, 0.f}, acc1 = acc0;
#pragma unroll
      for (int kt = 0; kt < 16; ++kt) {
        uint4 braw = *reinterpret_cast<const uint4*>(
            w1bf + ((kt * 32 + c16) * 512 + l15 * 32 + l4 * 8));
        bf16x8 b = __builtin_bit_cast(bf16x8, braw);
        acc0 = __builtin_amdgcn_mfma_f32_16x16x32_bf16(
                 __builtin_bit_cast(bf16x8, A0[kt]), b, acc0, 0, 0, 0);
        acc1 = __builtin_amdgcn_mfma_f32_16x16x32_bf16(
                 __builtin_bit_cast(bf16x8, A1[kt]), b, acc1, 0, 0, 0);
      }
      const int col = c16 * 16 + l15;
      const float bc = b1[col];
#pragma unroll
      for (int ri = 0; ri < 4; ++ri) {
        int b0 = l4 * 4 + ri;
        d1_bf[((b0)      * NT + (t - 1)) * NU + col] = f2bf(acc0[ri] + bc);
        d1_bf[((b0 + 16) * NT + (t - 1)) * NU + col] = f2bf(acc1[ri] + bc);
      }
    }
  }
}

// ---------------------------------------------------------------------------
// score+softmax: one wave per (b,t); softmax over lanes; store out[b][s][t].
// ---------------------------------------------------------------------------
__global__ __launch_bounds__(256, 1)
void score_kernel(const unsigned short* __restrict__ d1_bf,
                  const unsigned short* __restrict__ e2_bf,
                  const float* __restrict__ V,
                  float* __restrict__ out)
{
  const int tid = threadIdx.x;
  const int wave = tid >> 6, lane = tid & 63;
  const int p = blockIdx.x * 4 + wave;   // 0..2047
  const int bb = p >> 6, t = p & 63;

  union { uint4 q; unsigned short us[8]; } dv;
  dv.q = *reinterpret_cast<const uint4*>(d1_bf + (bb * 64 + t) * NU + lane * 8);
  float d1f[8], Vf[8];
#pragma unroll
  for (int e = 0; e < 8; ++e) { d1f[e] = bf2f(dv.us[e]); Vf[e] = V[lane * 8 + e]; }

  float sc = 0.f;
  for (int s = 0; s < NS; ++s) {
    union { uint4 q; unsigned short us[8]; } ev;
    ev.q = *reinterpret_cast<const uint4*>(e2_bf + (bb * 64 + s) * NU + lane * 8);
    float part = 0.f;
#pragma unroll
    for (int e = 0; e < 8; ++e) part += tanhfast(d1f[e] + bf2f(ev.us[e])) * Vf[e];
#pragma unroll
    for (int o = 32; o > 0; o >>= 1) part += __shfl_xor(part, o);
    sc = (lane == s) ? part : sc;
  }
  float m = sc;
#pragma unroll
  for (int o = 32; o > 0; o >>= 1) m = fmaxf(m, __shfl_xor(m, o));
  float ex = __expf(sc - m);
  float sum = ex;
#pragma unroll
  for (int o = 32; o > 0; o >>= 1) sum += __shfl_xor(sum, o);
  out[(bb * 64 + lane) * 64 + t] = ex / sum;
}

// ---------------------------------------------------------------------------
extern "C" void kernel_launch(void* const* d_in, const int* in_sizes, int n_in,
                              void* d_out, int out_size, void* d_ws, size_t ws_size,
                              hipStream_t stream)
{
  (void)in_sizes; (void)n_in; (void)out_size;
  const int*   labels = (const int*)  d_in[0];
  const float* enc    = (const float*)d_in[1];
  const float* h0     = (const float*)d_in[2];
  const float* c0     = (const float*)d_in[3];
  const float* Wx     = (const float*)d_in[4];
  const float* Wh     = (const float*)d_in[5];
  const float* bias   = (const float*)d_in[6];
  const float* W1     = (const float*)d_in[7];
  const float* b1     = (const float*)d_in[8];
  const float* W2     = (const float*)d_in[9];
  const float* b2     = (const float*)d_in[10];
  const float* V      = (const float*)d_in[11];
  // d_in[12] = bv: additive scalar on all scores -> softmax-invariant.

  char* ws = (char*)d_ws;
  const size_t OFS_W1B = 4096;                           // 512KB w1bf
  const size_t OFS_HB  = OFS_W1B + 524288;               // 65 x 32KB hbuf
  const size_t OFS_D1  = OFS_HB + (size_t)65 * 32768;    // 2MB d1
  const size_t OFS_E2  = OFS_D1 + (2u << 20);            // 2MB e2
  if (ws_size < OFS_E2 + (2u << 20)) return;             // ~6.9MB needed

  u32* flags = (u32*)(ws);
  unsigned short* w1bf = (unsigned short*)(ws + OFS_W1B);
  u32* hbuf  = (u32*)(ws + OFS_HB);
  unsigned short* d1_bf = (unsigned short*)(ws + OFS_D1);
  unsigned short* e2_bf = (unsigned short*)(ws + OFS_E2);
  float* out = (float*)d_out;

  prep_kernel<<<dim3(32), dim3(256), 0, stream>>>(W1, w1bf, flags);
  lstm_kernel<<<dim3(64), dim3(256), 0, stream>>>(labels, h0, c0, Wx, Wh, bias,
                                                  enc, W2, b2, w1bf, b1,
                                                  hbuf, flags, d1_bf, e2_bf);
  score_kernel<<<dim3(512), dim3(256), 0, stream>>>(d1_bf, e2_bf, V, out);
}